// Round 1
// baseline (3216.508 us; speedup 1.0000x reference)
//
#include <hip/hip_runtime.h>
#include <math.h>

#define BB 8
#define C_IN 128
#define HH 192
#define WW 192
#define A_DIM 16

// ---------------- Kernel 1: global average pool  p[b,c] = mean(x[b,c,:,:]) --------------
__global__ void avgpool_kernel(const float* __restrict__ x, float* __restrict__ p) {
    int bc = blockIdx.x;                       // 0..1023  (b*128+c)
    const float4* xp = (const float4*)(x + (size_t)bc * (HH * WW));
    float s = 0.f;
    // 36864/4 = 9216 float4, 256 threads -> 36 iters each
    for (int i = threadIdx.x; i < (HH * WW) / 4; i += 256) {
        float4 v = xp[i];
        s += v.x + v.y + v.z + v.w;
    }
    for (int off = 32; off; off >>= 1) s += __shfl_down(s, off, 64);
    __shared__ float red[4];
    int lane = threadIdx.x & 63, wid = threadIdx.x >> 6;
    if (lane == 0) red[wid] = s;
    __syncthreads();
    if (threadIdx.x == 0)
        p[bc] = (red[0] + red[1] + red[2] + red[3]) * (1.0f / (HH * WW));
}

// ---------------- Kernel 2: attention MLP (one block) ------------------------------------
__global__ void attention_kernel(const float* __restrict__ p,
                                 const float* __restrict__ fc_w,
                                 const float* __restrict__ bn_g, const float* __restrict__ bn_b,
                                 const float* __restrict__ bn_m, const float* __restrict__ bn_v,
                                 const float* __restrict__ ch_w, const float* __restrict__ ch_b,
                                 const float* __restrict__ fl_w, const float* __restrict__ fl_b,
                                 const float* __restrict__ sp_w, const float* __restrict__ sp_b,
                                 float* __restrict__ ch, float* __restrict__ fl,
                                 float* __restrict__ sp) {
    __shared__ float pl[BB * C_IN];
    __shared__ float yl[BB * A_DIM];
    int t = threadIdx.x;
    for (int i = t; i < BB * C_IN; i += 256) pl[i] = p[i];
    __syncthreads();
    if (t < BB * A_DIM) {
        int b = t / A_DIM, a = t % A_DIM;
        float s = 0.f;
        for (int c = 0; c < C_IN; ++c) s += pl[b * C_IN + c] * fc_w[a * C_IN + c];
        s = (s - bn_m[a]) * rsqrtf(bn_v[a] + 1e-5f) * bn_g[a] + bn_b[a];
        yl[t] = fmaxf(s, 0.f);
    }
    __syncthreads();
    for (int idx = t; idx < BB * C_IN; idx += 256) {
        int b = idx / C_IN, c = idx % C_IN;
        float s1 = ch_b[c], s2 = fl_b[c];
        for (int a = 0; a < A_DIM; ++a) {
            float yv = yl[b * A_DIM + a];
            s1 += yv * ch_w[c * A_DIM + a];
            s2 += yv * fl_w[c * A_DIM + a];
        }
        ch[idx] = 1.f / (1.f + expf(-s1));
        fl[idx] = 1.f / (1.f + expf(-s2));
    }
    if (t < BB * 9) {
        int b = t / 9, k = t % 9;
        float s = sp_b[k];
        for (int a = 0; a < A_DIM; ++a) s += yl[b * A_DIM + a] * sp_w[k * A_DIM + a];
        sp[t] = 1.f / (1.f + expf(-s));
    }
}

// ---------------- Kernel 3: build padded effective weights -------------------------------
// W_eff[b][o][i][12] = fl[b,o]*ch[b,i]*sp[b,tap]*od[o,i,tap]   (taps 0..8, pad 9..11 = 0)
// plus repack conv2_w -> w2p[o][i][12]
__global__ void prep_weights(const float* __restrict__ od, const float* __restrict__ w2,
                             const float* __restrict__ ch, const float* __restrict__ fl,
                             const float* __restrict__ sp,
                             float* __restrict__ weff, float* __restrict__ w2p) {
    int g = blockIdx.x * 256 + threadIdx.x;    // 0 .. 147455  ( (8+1)*128*128 )
    int bidx = g >> 14;                        // /16384
    int oi = g & 16383;
    float out[12];
    out[9] = out[10] = out[11] = 0.f;
    if (bidx < 8) {
        int o = oi >> 7, i = oi & 127;
        float s = fl[bidx * 128 + o] * ch[bidx * 128 + i];
#pragma unroll
        for (int t = 0; t < 9; ++t) out[t] = od[oi * 9 + t] * s * sp[bidx * 9 + t];
        float* dp = weff + (size_t)g * 12;
#pragma unroll
        for (int t = 0; t < 12; ++t) dp[t] = out[t];
    } else {
#pragma unroll
        for (int t = 0; t < 9; ++t) out[t] = w2[oi * 9 + t];
        float* dp = w2p + (size_t)oi * 12;
#pragma unroll
        for (int t = 0; t < 12; ++t) dp[t] = out[t];
    }
}

// ---------------- Kernels 4/5: direct 3x3 conv, 32x32 pixel tile, 16 oc / block ----------
// EPI=false: per-sample weights (W_eff), plain output (y1)
// EPI=true : shared weights (w2p), + bias + exact GELU + residual
#define OTILE 16
#define CH_I 2

template <bool EPI>
__global__ __launch_bounds__(256) void conv3x3(const float* __restrict__ src,
                                               const float* __restrict__ wts,
                                               const float* __restrict__ bias,
                                               const float* __restrict__ xres,
                                               float* __restrict__ dst) {
    __shared__ float lds[CH_I][34][34];
    const int tile = blockIdx.x;      // 0..35
    const int ochunk = blockIdx.y;    // 0..7
    const int b = blockIdx.z;         // 0..7
    const int th = tile / 6, tw = tile % 6;
    const int h0 = th * 32, w0 = tw * 32;
    const int tid = threadIdx.x;
    const int ty = tid >> 4, tx = tid & 15;
    const int ph = ty * 2, pw = tx * 2;   // 2x2 pixels per thread

    float acc[OTILE][2][2];
#pragma unroll
    for (int o = 0; o < OTILE; ++o)
#pragma unroll
        for (int r = 0; r < 2; ++r)
#pragma unroll
            for (int c = 0; c < 2; ++c) acc[o][r][c] = 0.f;

    const float* wb = wts + (EPI ? (size_t)0 : (size_t)b * (C_IN * C_IN * 12)) +
                      (size_t)(ochunk * OTILE) * (C_IN * 12);
    const float* srcb = src + (size_t)b * (C_IN * HH * WW);

    for (int i0 = 0; i0 < C_IN; i0 += CH_I) {
        __syncthreads();
        for (int idx = tid; idx < CH_I * 34 * 34; idx += 256) {
            int c = idx / (34 * 34);
            int rem = idx - c * 34 * 34;
            int r = rem / 34, q = rem - r * 34;
            int gh = h0 - 1 + r, gw = w0 - 1 + q;
            float v = 0.f;
            if ((unsigned)gh < HH && (unsigned)gw < WW)
                v = srcb[(size_t)(i0 + c) * (HH * WW) + gh * WW + gw];
            lds[c][r][q] = v;
        }
        __syncthreads();
#pragma unroll
        for (int ii = 0; ii < CH_I; ++ii) {
            float xv[4][4];
#pragma unroll
            for (int r = 0; r < 4; ++r) {
                float2 a_ = *(const float2*)&lds[ii][ph + r][pw];
                float2 b_ = *(const float2*)&lds[ii][ph + r][pw + 2];
                xv[r][0] = a_.x; xv[r][1] = a_.y; xv[r][2] = b_.x; xv[r][3] = b_.y;
            }
            const float* wp = wb + (i0 + ii) * 12;
#pragma unroll
            for (int o = 0; o < OTILE; ++o) {
                const float* w9 = wp + (size_t)o * (C_IN * 12);
                float4 wa = *(const float4*)(w9);
                float4 wbv = *(const float4*)(w9 + 4);
                float w8 = w9[8];
                float wv[9] = {wa.x, wa.y, wa.z, wa.w, wbv.x, wbv.y, wbv.z, wbv.w, w8};
#pragma unroll
                for (int kh = 0; kh < 3; ++kh)
#pragma unroll
                    for (int kw = 0; kw < 3; ++kw) {
                        float wt = wv[kh * 3 + kw];
#pragma unroll
                        for (int r = 0; r < 2; ++r)
#pragma unroll
                            for (int c = 0; c < 2; ++c)
                                acc[o][r][c] = fmaf(xv[r + kh][c + kw], wt, acc[o][r][c]);
                    }
            }
        }
    }
    // epilogue
#pragma unroll
    for (int o = 0; o < OTILE; ++o) {
        int oc = ochunk * OTILE + o;
        float bv = EPI ? bias[oc] : 0.f;
#pragma unroll
        for (int r = 0; r < 2; ++r) {
            int h = h0 + ph + r, w = w0 + pw;
            size_t oidx = (((size_t)b * C_IN + oc) * HH + h) * WW + w;
            float v0 = acc[o][r][0], v1 = acc[o][r][1];
            float2 v2;
            if (EPI) {
                v0 += bv; v1 += bv;
                float g0 = 0.5f * v0 * (1.f + erff(v0 * 0.70710678118654752f));
                float g1 = 0.5f * v1 * (1.f + erff(v1 * 0.70710678118654752f));
                float2 xr = *(const float2*)&xres[oidx];
                v2.x = xr.x + g0;
                v2.y = xr.y + g1;
            } else {
                v2.x = v0; v2.y = v1;
            }
            *(float2*)&dst[oidx] = v2;
        }
    }
}

extern "C" void kernel_launch(void* const* d_in, const int* in_sizes, int n_in,
                              void* d_out, int out_size, void* d_ws, size_t ws_size,
                              hipStream_t stream) {
    const float* x       = (const float*)d_in[0];
    const float* od      = (const float*)d_in[1];
    const float* fc_w    = (const float*)d_in[2];
    const float* bn_g    = (const float*)d_in[3];
    const float* bn_b    = (const float*)d_in[4];
    const float* bn_m    = (const float*)d_in[5];
    const float* bn_v    = (const float*)d_in[6];
    const float* ch_w    = (const float*)d_in[7];
    const float* ch_b    = (const float*)d_in[8];
    const float* fl_w    = (const float*)d_in[9];
    const float* fl_b    = (const float*)d_in[10];
    const float* sp_w    = (const float*)d_in[11];
    const float* sp_b    = (const float*)d_in[12];
    const float* conv2_w = (const float*)d_in[13];
    const float* conv2_b = (const float*)d_in[14];
    float* out = (float*)d_out;

    float* ws   = (float*)d_ws;
    float* y1   = ws;                        // 8*128*192*192      = 37,748,736
    float* weff = y1 + 37748736;             // 8*128*128*12       =  1,572,864
    float* w2p  = weff + 1572864;            // 128*128*12         =    196,608
    float* pbuf = w2p + 196608;              // 1024
    float* chb  = pbuf + 1024;               // 1024
    float* flb  = chb + 1024;                // 1024
    float* spb  = flb + 1024;                // 72

    avgpool_kernel<<<1024, 256, 0, stream>>>(x, pbuf);
    attention_kernel<<<1, 256, 0, stream>>>(pbuf, fc_w, bn_g, bn_b, bn_m, bn_v,
                                            ch_w, ch_b, fl_w, fl_b, sp_w, sp_b,
                                            chb, flb, spb);
    prep_weights<<<576, 256, 0, stream>>>(od, conv2_w, chb, flb, spb, weff, w2p);
    conv3x3<false><<<dim3(36, 8, 8), 256, 0, stream>>>(x, weff, nullptr, nullptr, y1);
    conv3x3<true><<<dim3(36, 8, 8), 256, 0, stream>>>(y1, w2p, conv2_b, x, out);
}

// Round 2
// 690.528 us; speedup vs baseline: 4.6580x; 4.6580x over previous
//
#include <hip/hip_runtime.h>
#include <math.h>

typedef short bf16x8 __attribute__((ext_vector_type(8)));
typedef float f32x4 __attribute__((ext_vector_type(4)));
typedef unsigned short u16;
typedef unsigned int u32;

#define BB 8
#define C_IN 128
#define HH 192
#define WW 192
#define A_DIM 16
#define HW_ (192 * 192)

__device__ __forceinline__ u16 f2b(float f) {
    u32 u = __float_as_uint(f);
    return (u16)((u + 0x7fffu + ((u >> 16) & 1u)) >> 16);
}
__device__ __forceinline__ float b2f(u16 u) {
    return __uint_as_float(((u32)u) << 16);
}

// ---------------- Kernel 1: global average pool ------------------------------------------
__global__ void avgpool_kernel(const float* __restrict__ x, float* __restrict__ p) {
    int bc = blockIdx.x;
    const float4* xp = (const float4*)(x + (size_t)bc * HW_);
    float s = 0.f;
    for (int i = threadIdx.x; i < HW_ / 4; i += 256) {
        float4 v = xp[i];
        s += v.x + v.y + v.z + v.w;
    }
    for (int off = 32; off; off >>= 1) s += __shfl_down(s, off, 64);
    __shared__ float red[4];
    int lane = threadIdx.x & 63, wid = threadIdx.x >> 6;
    if (lane == 0) red[wid] = s;
    __syncthreads();
    if (threadIdx.x == 0)
        p[bc] = (red[0] + red[1] + red[2] + red[3]) * (1.0f / HW_);
}

// ---------------- Kernel 2: attention MLP (one block) ------------------------------------
__global__ void attention_kernel(const float* __restrict__ p,
                                 const float* __restrict__ fc_w,
                                 const float* __restrict__ bn_g, const float* __restrict__ bn_b,
                                 const float* __restrict__ bn_m, const float* __restrict__ bn_v,
                                 const float* __restrict__ ch_w, const float* __restrict__ ch_b,
                                 const float* __restrict__ fl_w, const float* __restrict__ fl_b,
                                 const float* __restrict__ sp_w, const float* __restrict__ sp_b,
                                 float* __restrict__ ch, float* __restrict__ fl,
                                 float* __restrict__ sp) {
    __shared__ float pl[BB * C_IN];
    __shared__ float yl[BB * A_DIM];
    int t = threadIdx.x;
    for (int i = t; i < BB * C_IN; i += 256) pl[i] = p[i];
    __syncthreads();
    if (t < BB * A_DIM) {
        int b = t / A_DIM, a = t % A_DIM;
        float s = 0.f;
        for (int c = 0; c < C_IN; ++c) s += pl[b * C_IN + c] * fc_w[a * C_IN + c];
        s = (s - bn_m[a]) * rsqrtf(bn_v[a] + 1e-5f) * bn_g[a] + bn_b[a];
        yl[t] = fmaxf(s, 0.f);
    }
    __syncthreads();
    for (int idx = t; idx < BB * C_IN; idx += 256) {
        int b = idx / C_IN, c = idx % C_IN;
        float s1 = ch_b[c], s2 = fl_b[c];
        for (int a = 0; a < A_DIM; ++a) {
            float yv = yl[b * A_DIM + a];
            s1 += yv * ch_w[c * A_DIM + a];
            s2 += yv * fl_w[c * A_DIM + a];
        }
        ch[idx] = 1.f / (1.f + expf(-s1));
        fl[idx] = 1.f / (1.f + expf(-s2));
    }
    if (t < BB * 9) {
        int b = t / 9, k = t % 9;
        float s = sp_b[k];
        for (int a = 0; a < A_DIM; ++a) s += yl[b * A_DIM + a] * sp_w[k * A_DIM + a];
        sp[t] = 1.f / (1.f + expf(-s));
    }
}

// ---------------- Kernel 3: build bf16 weight chunks -------------------------------------
// Layout: per (b, ic, tap): [o=128][i_pad=40] bf16 (= 10240 B contiguous, lds-stage unit).
// i in chunk: ii 0..31 real (i = ic*32+ii), 32..39 zero pad (pitch 80 B -> 2-way LDS banks).
// bidx 0..7: weff = fl[b,o]*ch[b,i]*sp[b,tap]*od[o,i,tap];  bidx 8: conv2_w.
__global__ void prep_w(const float* __restrict__ od, const float* __restrict__ w2,
                       const float* __restrict__ ch, const float* __restrict__ fl,
                       const float* __restrict__ sp,
                       u16* __restrict__ wp, u16* __restrict__ w2p) {
    int t = blockIdx.x * 256 + threadIdx.x;  // 9*4*128*40 = 184320 exactly
    int ii = t % 40;
    int r = t / 40;
    int o = r % 128; r /= 128;
    int ic = r & 3;
    int bidx = r >> 2;
    size_t cbase = (size_t)(ic * 9) * 5120 + o * 40 + ii;
    u16* dst = (bidx < 8) ? (wp + (size_t)bidx * 184320 + cbase) : (w2p + cbase);
    if (ii >= 32) {
#pragma unroll
        for (int tap = 0; tap < 9; ++tap) dst[(size_t)tap * 5120] = 0;
        return;
    }
    int i = ic * 32 + ii;
    if (bidx < 8) {
        float s = fl[bidx * 128 + o] * ch[bidx * 128 + i];
#pragma unroll
        for (int tap = 0; tap < 9; ++tap) {
            float v = od[((size_t)o * 128 + i) * 9 + tap] * s * sp[bidx * 9 + tap];
            dst[(size_t)tap * 5120] = f2b(v);
        }
    } else {
#pragma unroll
        for (int tap = 0; tap < 9; ++tap)
            dst[(size_t)tap * 5120] = f2b(w2[((size_t)o * 128 + i) * 9 + tap]);
    }
}

// ---------------- Kernels 4/5: MFMA implicit-GEMM 3x3 conv -------------------------------
// Block: 8x16 pixel tile (haloed 10x18=180), all 128 out channels, batch b.
// 4 waves, 2M x 2N; per wave M=64 (4 msub), N=64px (4 h-rows of 16w).
// K-loop: 4 input-ch chunks (32) x 9 taps; one mfma k=32 step per (chunk,tap).
// X: reg-staged (fp32/bf16 -> bf16) into [g8][180px][8ch] (16B rows, conflict-free).
// W: global_load_lds x16 into double-buffered [128o][40i] (80B pitch, 2-way free).
template <bool EPI, bool SBF>
__global__ __launch_bounds__(256, 3) void convk(const void* __restrict__ srcv,
                                                const u16* __restrict__ wgl,
                                                const float* __restrict__ bias,
                                                const float* __restrict__ xres,
                                                void* __restrict__ dstv) {
    __shared__ __align__(16) u16 xbuf[2][4][180][8];
    __shared__ __align__(16) u16 wbuf[2][5120];

    const int tid = threadIdx.x;
    const int lane = tid & 63;
    const int wid = tid >> 6;
    const int lcol = lane & 15, klane = lane >> 4;
    const int wave_m = wid >> 1, wave_n = wid & 1;
    const int tile = blockIdx.x, b = blockIdx.y;
    const int h0 = (tile / 12) * 8, w0 = (tile % 12) * 16;

    const char* wsrc = (const char*)(EPI ? wgl : (wgl + (size_t)b * 184320));

    float xr[3][8];

    auto stageW = [&](int phase) {
        const char* g = wsrc + (size_t)phase * 10240;
        char* l = (char*)&wbuf[phase & 1][0];
#pragma unroll
        for (int r = 0; r < 3; ++r) {
            int off = (wid + r * 4) << 10;
            if (off < 10240)
                __builtin_amdgcn_global_load_lds(
                    (const __attribute__((address_space(1))) void*)(g + off + lane * 16),
                    (__attribute__((address_space(3))) void*)(l + off), 16, 0, 0);
        }
    };
    auto stageXload = [&](int c) {
#pragma unroll
        for (int it = 0; it < 3; ++it) {
            int idx = tid + it * 256;
            if (idx < 720) {
                int g = idx / 180, pp = idx - g * 180;
                int gh = h0 - 1 + pp / 18, gw = w0 - 1 + pp % 18;
                bool ok = ((unsigned)gh < 192u) && ((unsigned)gw < 192u);
#pragma unroll
                for (int j = 0; j < 8; ++j) {
                    float v = 0.f;
                    if (ok) {
                        size_t a = (((size_t)b * 128 + c * 32 + g * 8 + j) * 192 + gh) * 192 + gw;
                        v = SBF ? b2f(((const u16*)srcv)[a]) : ((const float*)srcv)[a];
                    }
                    xr[it][j] = v;
                }
            }
        }
    };
    auto stageXwrite = [&](int buf) {
#pragma unroll
        for (int it = 0; it < 3; ++it) {
            int idx = tid + it * 256;
            if (idx < 720) {
                int g = idx / 180, pp = idx - g * 180;
                union { u16 u[8]; uint4 v; } pk;
#pragma unroll
                for (int j = 0; j < 8; ++j) pk.u[j] = f2b(xr[it][j]);
                *(uint4*)&xbuf[buf][g][pp][0] = pk.v;
            }
        }
    };

    f32x4 acc[4][4];
#pragma unroll
    for (int m = 0; m < 4; ++m)
#pragma unroll
        for (int n = 0; n < 4; ++n) acc[m][n] = (f32x4){0.f, 0.f, 0.f, 0.f};

    // prologue: X chunk 0 + W phase 0
    stageXload(0);
    stageW(0);
    stageXwrite(0);
    __syncthreads();

    for (int ic = 0; ic < 4; ++ic) {
        if (ic < 3) stageXload(ic + 1);  // global loads in flight over this chunk's taps
#pragma unroll
        for (int tap = 0; tap < 9; ++tap) {
            const int phase = ic * 9 + tap;
            if (phase + 1 < 36) stageW(phase + 1);
            const int dh = tap / 3, dw = tap % 3;
            bf16x8 af[4], bfr[4];
            const u16* wb_ = &wbuf[(ic + tap) & 1][0];
#pragma unroll
            for (int m = 0; m < 4; ++m)
                af[m] = *(const bf16x8*)&wb_[(wave_m * 64 + m * 16 + lcol) * 40 + klane * 8];
#pragma unroll
            for (int n = 0; n < 4; ++n) {
                int pp = (wave_n * 4 + n + dh) * 18 + lcol + dw;
                bfr[n] = *(const bf16x8*)&xbuf[ic & 1][klane][pp][0];
            }
#pragma unroll
            for (int m = 0; m < 4; ++m)
#pragma unroll
                for (int n = 0; n < 4; ++n)
                    acc[m][n] = __builtin_amdgcn_mfma_f32_16x16x32_bf16(af[m], bfr[n],
                                                                        acc[m][n], 0, 0, 0);
            if (tap == 8 && ic < 3) stageXwrite((ic + 1) & 1);
            __syncthreads();
        }
    }

    // epilogue: D frag -> (o = row, pixel = col)
#pragma unroll
    for (int m = 0; m < 4; ++m) {
        const int o = wave_m * 64 + m * 16 + klane * 4;
#pragma unroll
        for (int n = 0; n < 4; ++n) {
            const int h = h0 + wave_n * 4 + n;
            const int w = w0 + lcol;
            size_t base = (((size_t)b * 128 + o) * 192 + h) * 192 + w;
#pragma unroll
            for (int r = 0; r < 4; ++r) {
                float v = acc[m][n][r];
                size_t adr = base + (size_t)r * HW_;
                if (EPI) {
                    v += bias[o + r];
                    float ge = 0.5f * v * (1.f + erff(v * 0.70710678118654752f));
                    ((float*)dstv)[adr] = xres[adr] + ge;
                } else {
                    ((u16*)dstv)[adr] = f2b(v);
                }
            }
        }
    }
}

extern "C" void kernel_launch(void* const* d_in, const int* in_sizes, int n_in,
                              void* d_out, int out_size, void* d_ws, size_t ws_size,
                              hipStream_t stream) {
    const float* x       = (const float*)d_in[0];
    const float* od      = (const float*)d_in[1];
    const float* fc_w    = (const float*)d_in[2];
    const float* bn_g    = (const float*)d_in[3];
    const float* bn_b    = (const float*)d_in[4];
    const float* bn_m    = (const float*)d_in[5];
    const float* bn_v    = (const float*)d_in[6];
    const float* ch_w    = (const float*)d_in[7];
    const float* ch_b    = (const float*)d_in[8];
    const float* fl_w    = (const float*)d_in[9];
    const float* fl_b    = (const float*)d_in[10];
    const float* sp_w    = (const float*)d_in[11];
    const float* sp_b    = (const float*)d_in[12];
    const float* conv2_w = (const float*)d_in[13];
    const float* conv2_b = (const float*)d_in[14];
    float* out = (float*)d_out;

    char* wsb = (char*)d_ws;
    u16* y1  = (u16*)wsb;                                   // 8*128*192*192*2 = 75,497,472 B
    u16* wp  = (u16*)(wsb + 75497472);                      // 8*184320*2      =  2,949,120 B
    u16* w2p = (u16*)(wsb + 75497472 + 2949120);            // 184320*2        =    368,640 B
    float* pbuf = (float*)(wsb + 75497472 + 2949120 + 368640);
    float* chb  = pbuf + 1024;
    float* flb  = chb + 1024;
    float* spb  = flb + 1024;

    avgpool_kernel<<<1024, 256, 0, stream>>>(x, pbuf);
    attention_kernel<<<1, 256, 0, stream>>>(pbuf, fc_w, bn_g, bn_b, bn_m, bn_v,
                                            ch_w, ch_b, fl_w, fl_b, sp_w, sp_b,
                                            chb, flb, spb);
    prep_w<<<720, 256, 0, stream>>>(od, conv2_w, chb, flb, spb, wp, w2p);
    convk<false, false><<<dim3(288, 8), 256, 0, stream>>>(x, wp, nullptr, nullptr, y1);
    convk<true, true><<<dim3(288, 8), 256, 0, stream>>>(y1, w2p, conv2_b, x, out);
}

// Round 3
// 686.935 us; speedup vs baseline: 4.6824x; 1.0052x over previous
//
#include <hip/hip_runtime.h>
#include <math.h>

typedef short bf16x8 __attribute__((ext_vector_type(8)));
typedef float f32x4 __attribute__((ext_vector_type(4)));
typedef unsigned short u16;
typedef unsigned int u32;

#define BB 8
#define C_IN 128
#define HH 192
#define WW 192
#define A_DIM 16
#define HW_ (192 * 192)

__device__ __forceinline__ u16 f2b(float f) {
    u32 u = __float_as_uint(f);
    return (u16)((u + 0x7fffu + ((u >> 16) & 1u)) >> 16);
}
__device__ __forceinline__ float b2f(u16 u) {
    return __uint_as_float(((u32)u) << 16);
}

// ---------------- Kernel 1: global average pool ------------------------------------------
__global__ void avgpool_kernel(const float* __restrict__ x, float* __restrict__ p) {
    int bc = blockIdx.x;
    const float4* xp = (const float4*)(x + (size_t)bc * HW_);
    float s = 0.f;
    for (int i = threadIdx.x; i < HW_ / 4; i += 256) {
        float4 v = xp[i];
        s += v.x + v.y + v.z + v.w;
    }
    for (int off = 32; off; off >>= 1) s += __shfl_down(s, off, 64);
    __shared__ float red[4];
    int lane = threadIdx.x & 63, wid = threadIdx.x >> 6;
    if (lane == 0) red[wid] = s;
    __syncthreads();
    if (threadIdx.x == 0)
        p[bc] = (red[0] + red[1] + red[2] + red[3]) * (1.0f / HW_);
}

// ---------------- Kernel 2: attention MLP (one block) ------------------------------------
__global__ void attention_kernel(const float* __restrict__ p,
                                 const float* __restrict__ fc_w,
                                 const float* __restrict__ bn_g, const float* __restrict__ bn_b,
                                 const float* __restrict__ bn_m, const float* __restrict__ bn_v,
                                 const float* __restrict__ ch_w, const float* __restrict__ ch_b,
                                 const float* __restrict__ fl_w, const float* __restrict__ fl_b,
                                 const float* __restrict__ sp_w, const float* __restrict__ sp_b,
                                 float* __restrict__ ch, float* __restrict__ fl,
                                 float* __restrict__ sp) {
    __shared__ float pl[BB * C_IN];
    __shared__ float yl[BB * A_DIM];
    int t = threadIdx.x;
    for (int i = t; i < BB * C_IN; i += 256) pl[i] = p[i];
    __syncthreads();
    if (t < BB * A_DIM) {
        int b = t / A_DIM, a = t % A_DIM;
        float s = 0.f;
        for (int c = 0; c < C_IN; ++c) s += pl[b * C_IN + c] * fc_w[a * C_IN + c];
        s = (s - bn_m[a]) * rsqrtf(bn_v[a] + 1e-5f) * bn_g[a] + bn_b[a];
        yl[t] = fmaxf(s, 0.f);
    }
    __syncthreads();
    for (int idx = t; idx < BB * C_IN; idx += 256) {
        int b = idx / C_IN, c = idx % C_IN;
        float s1 = ch_b[c], s2 = fl_b[c];
        for (int a = 0; a < A_DIM; ++a) {
            float yv = yl[b * A_DIM + a];
            s1 += yv * ch_w[c * A_DIM + a];
            s2 += yv * fl_w[c * A_DIM + a];
        }
        ch[idx] = 1.f / (1.f + expf(-s1));
        fl[idx] = 1.f / (1.f + expf(-s2));
    }
    if (t < BB * 9) {
        int b = t / 9, k = t % 9;
        float s = sp_b[k];
        for (int a = 0; a < A_DIM; ++a) s += yl[b * A_DIM + a] * sp_w[k * A_DIM + a];
        sp[t] = 1.f / (1.f + expf(-s));
    }
}

// ---------------- Kernel 3: build bf16 weights in MFMA-fragment order --------------------
// Per (bidx, ic, tap): 8192-B block. Element (o, i=kl*8+j) at 16B-slot
// ((o>>4)*64 + kl*16 + (o&15)), j packed within the slot. This is exactly the per-lane
// ds_read_b128 order of the conv kernel (lane = klane*16 + lcol) -> conflict-free reads.
__global__ void prep_w(const float* __restrict__ od, const float* __restrict__ w2,
                       const float* __restrict__ ch, const float* __restrict__ fl,
                       const float* __restrict__ sp,
                       u16* __restrict__ wp, u16* __restrict__ w2p) {
    int t = blockIdx.x * 256 + threadIdx.x;   // 9*4*9*128*4 = 165,888 exactly
    int kl = t & 3;
    int q = t >> 2;
    int o = q & 127; q >>= 7;
    int tap = q % 9; q /= 9;
    int ic = q & 3;
    int bidx = q >> 2;

    u16* base = (bidx < 8) ? (wp + (size_t)bidx * 147456) : w2p;
    u16* dst = base + (size_t)(ic * 9 + tap) * 4096 +
               (size_t)((o >> 4) * 64 + kl * 16 + (o & 15)) * 8;

    union { u16 u[8]; uint4 v; } pk;
    if (bidx < 8) {
        float s = fl[bidx * 128 + o] * sp[bidx * 9 + tap];
#pragma unroll
        for (int j = 0; j < 8; ++j) {
            int i = ic * 32 + kl * 8 + j;
            float v = od[((size_t)o * 128 + i) * 9 + tap] * s * ch[bidx * 128 + i];
            pk.u[j] = f2b(v);
        }
    } else {
#pragma unroll
        for (int j = 0; j < 8; ++j) {
            int i = ic * 32 + kl * 8 + j;
            pk.u[j] = f2b(w2[((size_t)o * 128 + i) * 9 + tap]);
        }
    }
    *(uint4*)dst = pk.v;
}

// ---------------- Kernels 4/5: MFMA implicit-GEMM 3x3 conv, counted-vmcnt pipeline -------
// Tile 8x16 px (halo 10x18=180), 128 out ch, 4 waves (2M x 2N), acc 4x4 per wave.
// K-loop: 4 ic-chunks x 9 taps = 36 phases. W: depth-3 prefetch into wbuf[4] via
// global_load_lds (2/wave/phase, uniform), raw s_barrier + hand-counted s_waitcnt vmcnt.
// X: single LDS buffer, reg-prefetch (24 loads/wave, count-uniform via addr clamping)
// issued at tap 5, written at chunk boundary (T14).
#define WAITV(N) asm volatile("s_waitcnt vmcnt(" #N ")" ::: "memory")

template <bool EPI, bool SBF>
__global__ __launch_bounds__(256, 3) void convk(const void* __restrict__ srcv,
                                                const u16* __restrict__ wgl,
                                                const float* __restrict__ bias,
                                                const float* __restrict__ xres,
                                                void* __restrict__ dstv) {
    __shared__ __align__(16) u16 xbuf[4][180][8];   // 11,520 B
    __shared__ __align__(16) u16 wbuf[4][4096];     // 4 x 8,192 B

    const int tid = threadIdx.x;
    const int lane = tid & 63;
    const int wid = tid >> 6;
    const int lcol = lane & 15, klane = lane >> 4;
    const int wave_m = wid >> 1, wave_n = wid & 1;
    const int tile = blockIdx.x, b = blockIdx.y;
    const int h0 = (tile / 12) * 8, w0 = (tile % 12) * 16;

    const char* wsrc = (const char*)(EPI ? wgl : (wgl + (size_t)b * 147456));

    float xr[3][8];

    auto issueW = [&](int p) {  // exactly 2 global_load_lds per wave
        const char* g = wsrc + (size_t)p * 8192;
        char* l = (char*)&wbuf[p & 3][0];
        int off = wid << 10;
        __builtin_amdgcn_global_load_lds(
            (const __attribute__((address_space(1))) void*)(g + off + lane * 16),
            (__attribute__((address_space(3))) void*)(l + off), 16, 0, 0);
        off += 4096;
        __builtin_amdgcn_global_load_lds(
            (const __attribute__((address_space(1))) void*)(g + off + lane * 16),
            (__attribute__((address_space(3))) void*)(l + off), 16, 0, 0);
    };
    auto loadX = [&](int c) {  // exactly 24 global loads per wave (clamped, no skip)
#pragma unroll
        for (int it = 0; it < 3; ++it) {
            int idx = tid + it * 256;
            if (idx < 720) {
                int g = idx / 180, pp = idx - g * 180;
                int gh = h0 - 1 + pp / 18, gw = w0 - 1 + pp % 18;
                bool ok = ((unsigned)gh < 192u) && ((unsigned)gw < 192u);
                int ghc = min(max(gh, 0), 191), gwc = min(max(gw, 0), 191);
#pragma unroll
                for (int j = 0; j < 8; ++j) {
                    size_t a = (((size_t)b * 128 + c * 32 + g * 8 + j) * 192 + ghc) * 192 + gwc;
                    float v = SBF ? b2f(((const u16*)srcv)[a]) : ((const float*)srcv)[a];
                    xr[it][j] = ok ? v : 0.f;
                }
            }
        }
    };
    auto writeX = [&]() {
#pragma unroll
        for (int it = 0; it < 3; ++it) {
            int idx = tid + it * 256;
            if (idx < 720) {
                int g = idx / 180, pp = idx - g * 180;
                union { u16 u[8]; uint4 v; } pk;
#pragma unroll
                for (int j = 0; j < 8; ++j) pk.u[j] = f2b(xr[it][j]);
                *(uint4*)&xbuf[g][pp][0] = pk.v;
            }
        }
    };

    f32x4 acc[4][4];
#pragma unroll
    for (int m = 0; m < 4; ++m)
#pragma unroll
        for (int n = 0; n < 4; ++n) acc[m][n] = (f32x4){0.f, 0.f, 0.f, 0.f};

    // ---- prologue: X(chunk0) issued first, then W(0..2); wait leaves {W1,W2} ----
    loadX(0);
    asm volatile("" ::: "memory");
    issueW(0); issueW(1); issueW(2);
    WAITV(4);                                   // XL + W0 complete
    writeX();
    asm volatile("s_waitcnt lgkmcnt(0)" ::: "memory");
    __builtin_amdgcn_sched_barrier(0);
    __builtin_amdgcn_s_barrier();

#pragma unroll
    for (int c = 0; c < 4; ++c) {
#pragma unroll
        for (int t = 0; t < 9; ++t) {
            const int p = c * 9 + t;
            const int dh = t / 3, dw = t % 3;

            bf16x8 af[4], bfr[4];
            const u16* wb_ = &wbuf[p & 3][0];
#pragma unroll
            for (int m = 0; m < 4; ++m)
                af[m] = *(const bf16x8*)&wb_[(size_t)((wave_m * 4 + m) * 64 + lane) * 8];
#pragma unroll
            for (int n = 0; n < 4; ++n) {
                int pp = (wave_n * 4 + n + dh) * 18 + lcol + dw;
                bfr[n] = *(const bf16x8*)&xbuf[klane][pp][0];
            }

            if (p + 3 < 36) issueW(p + 3);
            if (t == 5 && c < 3) {
                asm volatile("" ::: "memory");  // keep W(p+3) before XL in vmem FIFO
                loadX(c + 1);
            }

            __builtin_amdgcn_s_setprio(1);
#pragma unroll
            for (int m = 0; m < 4; ++m)
#pragma unroll
                for (int n = 0; n < 4; ++n)
                    acc[m][n] = __builtin_amdgcn_mfma_f32_16x16x32_bf16(af[m], bfr[n],
                                                                        acc[m][n], 0, 0, 0);
            __builtin_amdgcn_s_setprio(0);

            // end-of-phase wait: ensure W(p+1) landed; N = |ops issued after W(p+1)|
            if (p <= 34) {
                const int xl = (c < 3 && (t == 5 || t == 6 || t == 7)) ? 24 : 0;
                const int wn = ((p <= 33) ? 2 : 0) + ((p <= 32) ? 2 : 0) + xl;
                if (wn == 28) WAITV(28);
                else if (wn == 4) WAITV(4);
                else if (wn == 2) WAITV(2);
                else WAITV(0);
            }
            if (p < 35) __builtin_amdgcn_s_barrier();
            if (t == 8 && c < 3) {              // chunk boundary: publish new X
                writeX();
                asm volatile("s_waitcnt lgkmcnt(0)" ::: "memory");
                __builtin_amdgcn_sched_barrier(0);
                __builtin_amdgcn_s_barrier();
            }
        }
    }

    // ---- epilogue: D frag -> (o = row, pixel = col) ----
#pragma unroll
    for (int m = 0; m < 4; ++m) {
        const int o = wave_m * 64 + m * 16 + klane * 4;
#pragma unroll
        for (int n = 0; n < 4; ++n) {
            const int h = h0 + wave_n * 4 + n;
            const int w = w0 + lcol;
            size_t base = (((size_t)b * 128 + o) * 192 + h) * 192 + w;
#pragma unroll
            for (int r = 0; r < 4; ++r) {
                float v = acc[m][n][r];
                size_t adr = base + (size_t)r * HW_;
                if (EPI) {
                    v += bias[o + r];
                    float ge = 0.5f * v * (1.f + erff(v * 0.70710678118654752f));
                    ((float*)dstv)[adr] = xres[adr] + ge;
                } else {
                    ((u16*)dstv)[adr] = f2b(v);
                }
            }
        }
    }
}

extern "C" void kernel_launch(void* const* d_in, const int* in_sizes, int n_in,
                              void* d_out, int out_size, void* d_ws, size_t ws_size,
                              hipStream_t stream) {
    const float* x       = (const float*)d_in[0];
    const float* od      = (const float*)d_in[1];
    const float* fc_w    = (const float*)d_in[2];
    const float* bn_g    = (const float*)d_in[3];
    const float* bn_b    = (const float*)d_in[4];
    const float* bn_m    = (const float*)d_in[5];
    const float* bn_v    = (const float*)d_in[6];
    const float* ch_w    = (const float*)d_in[7];
    const float* ch_b    = (const float*)d_in[8];
    const float* fl_w    = (const float*)d_in[9];
    const float* fl_b    = (const float*)d_in[10];
    const float* sp_w    = (const float*)d_in[11];
    const float* sp_b    = (const float*)d_in[12];
    const float* conv2_w = (const float*)d_in[13];
    const float* conv2_b = (const float*)d_in[14];
    float* out = (float*)d_out;

    char* wsb = (char*)d_ws;
    u16* y1  = (u16*)wsb;                                   // 75,497,472 B
    u16* wp  = (u16*)(wsb + 75497472);                      // 8*294,912 B = 2,359,296
    u16* w2p = (u16*)(wsb + 75497472 + 2359296);            // 294,912 B
    float* pbuf = (float*)(wsb + 75497472 + 2359296 + 294912);
    float* chb  = pbuf + 1024;
    float* flb  = chb + 1024;
    float* spb  = flb + 1024;

    avgpool_kernel<<<1024, 256, 0, stream>>>(x, pbuf);
    attention_kernel<<<1, 256, 0, stream>>>(pbuf, fc_w, bn_g, bn_b, bn_m, bn_v,
                                            ch_w, ch_b, fl_w, fl_b, sp_w, sp_b,
                                            chb, flb, spb);
    prep_w<<<648, 256, 0, stream>>>(od, conv2_w, chb, flb, spb, wp, w2p);
    convk<false, false><<<dim3(288, 8), 256, 0, stream>>>(x, wp, nullptr, nullptr, y1);
    convk<true, true><<<dim3(288, 8), 256, 0, stream>>>(y1, w2p, conv2_b, x, out);
}